// Round 3
// baseline (285.313 us; speedup 1.0000x reference)
//
#include <hip/hip_runtime.h>
#include <math.h>

// Problem constants (match setup_inputs: B=128, T=262144).
#define B_    128
#define T_    262144
#define L_    16                 // samples per thread
#define NT_   256                // threads per block
#define WCH_  16                 // warmup chunks per tile (256 samples; A^256 ~ 1e-11)
#define OT_   (NT_ * L_)         // output tile = 4096 samples
#define TPR_  (T_ / OT_)         // 64 tiles per row
#define NW_   (NT_ / 64)         // 4 waves per block

typedef float f32x4 __attribute__((ext_vector_type(4)));

struct Coef {
    float bh0, bh1;              // highpass input coefs
    float p, q, r;               // transition matrix [[p,0],[q,r]]
    float blc0, blc1;            // y2 direct input coefs: bl0*bh0, bl0*bh1
};

// One IIR step; y1,y2 depend only on previous-iteration state (expanded form).
__device__ inline void iir_step(const Coef& c, float xt, float& x_prev,
                                float& y1, float& y2) {
    float c1 = fmaf(c.bh0,  xt, c.bh1  * x_prev);
    float cx = fmaf(c.blc0, xt, c.blc1 * x_prev);
    float ny1 = fmaf(c.p, y1, c1);
    float ny2 = fmaf(c.q, y1, fmaf(c.r, y2, cx));
    y1 = ny1; y2 = ny2; x_prev = xt;
}

// Lower-triangular 2x2 as (p,q,r) = [[p,0],[q,r]]. Powers of one A commute.
struct Mat { float p, q, r; };
__device__ inline Mat mat_sq(Mat m) {
    Mat o; o.p = m.p * m.p; o.q = m.q * (m.p + m.r); o.r = m.r * m.r; return o;
}
__device__ inline Mat mat_mul(Mat a, Mat b) {   // a*b
    Mat o; o.p = a.p * b.p; o.q = fmaf(a.q, b.p, a.r * b.q); o.r = a.r * b.r;
    return o;
}
__device__ inline float2 mat_apply_add(Mat m, float2 v, float2 add) {  // m*v+add
    float2 o;
    o.x = fmaf(m.p, v.x, add.x);
    o.y = fmaf(m.q, v.x, fmaf(m.r, v.y, add.y));
    return o;
}

__global__ __launch_bounds__(NT_, 4) void bp_kernel(
        const float* __restrict__ x, float* __restrict__ out,
        const float* __restrict__ cfp, const float* __restrict__ bwp,
        const float* __restrict__ gp, const int* __restrict__ srp) {
    __shared__ float2 wagg[WCH_];          // warmup chunk aggregates
    __shared__ float2 wsagg[NW_];          // per-wave scan aggregates

    const int blk  = blockIdx.x;
    const int row  = blk >> 6;             // / TPR_
    const int ti   = blk & (TPR_ - 1);
    const int t    = threadIdx.x;
    const int lane = t & 63;
    const int wav  = t >> 6;
    const long tile_start = (long)row * T_ + (long)ti * OT_;
    const float* xb = x + tile_start;

    // ---- Issue ALL global loads up-front (latency hidden under coef math).
    // Own segment: 16 contiguous floats = 4 float4 (64B-aligned).
    const f32x4* xg = (const f32x4*)(xb + t * L_);
    f32x4 v0 = xg[0], v1 = xg[1], v2 = xg[2], v3 = xg[3];
    // Boundary sample (last elem of previous chunk).
    float xp = (ti != 0 || t != 0) ? xb[t * L_ - 1] : 0.f;
    // Warmup segment for threads 0..15 (zeros for first tile of a row: exact).
    f32x4 w0 = (f32x4)(0.f), w1 = w0, w2 = w0, w3 = w0;
    float wxp = 0.f;
    if (t < WCH_ && ti != 0) {
        const f32x4* wg = (const f32x4*)(xb - WCH_ * L_ + t * L_);
        w0 = wg[0]; w1 = wg[1]; w2 = wg[2]; w3 = wg[3];
        if (t != 0) wxp = xb[-WCH_ * L_ + t * L_ - 1];
    }

    // ---- Filter coefficients, per-thread (uniform; overlaps load latency).
    Coef cf;
    {
        const float PIH = 1.57079632679489661923f;  // pi/2
        float cfv = *cfp, bwv = *bwp;
        float nyq = 0.5f * (float)(*srp);
        float K1 = tanf(PIH * (cfv - 0.5f * bwv) / nyq);
        float K2 = tanf(PIH * (cfv + 0.5f * bwv) / nyq);
        float inv1 = 1.0f / (K1 + 1.0f);
        float ah1 = (K1 - 1.0f) * inv1;
        float inv2 = 1.0f / (K2 + 1.0f);
        float bl0 = K2 * inv2;               // == bl1
        float al1 = (K2 - 1.0f) * inv2;
        cf.bh0 = inv1;
        cf.bh1 = -inv1;
        cf.p = -ah1;
        cf.q = bl0 - bl0 * ah1;              // bl0*(1 - ah1)
        cf.r = -al1;
        cf.blc0 = bl0 * inv1;
        cf.blc1 = -bl0 * inv1;
    }
    const float gain = *gp;

    // ---- Matrix powers (also overlaps load latency).
    Mat A  = { cf.p, cf.q, cf.r };
    Mat AL = A;
    #pragma unroll
    for (int k = 0; k < 4; ++k) AL = mat_sq(AL);        // A^16 = A^L
    // R = AL^lane by binary powers (6 bits).
    Mat R = { 1.f, 0.f, 1.f };
    {
        Mat Mp = AL;
        unsigned b = (unsigned)lane;
        #pragma unroll
        for (int k = 0; k < 6; ++k) {
            if (b & 1u) R = mat_mul(Mp, R);
            b >>= 1u;
            if (k < 5) Mp = mat_sq(Mp);
        }
    }

    // ---- Local scan of own chunk from zero state; y2 locals stay in VGPRs.
    float xa[L_];
    xa[0]=v0.x; xa[1]=v0.y; xa[2]=v0.z; xa[3]=v0.w;
    xa[4]=v1.x; xa[5]=v1.y; xa[6]=v1.z; xa[7]=v1.w;
    xa[8]=v2.x; xa[9]=v2.y; xa[10]=v2.z; xa[11]=v2.w;
    xa[12]=v3.x; xa[13]=v3.y; xa[14]=v3.z; xa[15]=v3.w;
    float y2l[L_];
    float y1 = 0.f, y2 = 0.f;
    {
        float xprev = xp;
        #pragma unroll
        for (int i = 0; i < L_; ++i) {
            iir_step(cf, xa[i], xprev, y1, y2);
            y2l[i] = y2;
        }
    }

    // ---- Warmup chunk scans: threads 0..15 (registers, no LDS input).
    if (t < WCH_) {
        float wa[L_];
        wa[0]=w0.x; wa[1]=w0.y; wa[2]=w0.z; wa[3]=w0.w;
        wa[4]=w1.x; wa[5]=w1.y; wa[6]=w1.z; wa[7]=w1.w;
        wa[8]=w2.x; wa[9]=w2.y; wa[10]=w2.z; wa[11]=w2.w;
        wa[12]=w3.x; wa[13]=w3.y; wa[14]=w3.z; wa[15]=w3.w;
        float wy1 = 0.f, wy2 = 0.f, wp = wxp;
        #pragma unroll
        for (int i = 0; i < L_; ++i) iir_step(cf, wa[i], wp, wy1, wy2);
        wagg[t] = make_float2(wy1, wy2);
    }

    // ---- Intra-wave inclusive scan via shuffles (no barriers).
    float2 a = make_float2(y1, y2);
    Mat Pw = AL;
    #pragma unroll
    for (int o = 1; o < 64; o <<= 1) {
        float vx = __shfl_up(a.x, (unsigned)o, 64);
        float vy = __shfl_up(a.y, (unsigned)o, 64);
        if (lane >= o) {
            a.y = fmaf(Pw.q, vx, fmaf(Pw.r, vy, a.y));
            a.x = fmaf(Pw.p, vx, a.x);
        }
        Pw = mat_sq(Pw);                                // after loop: A^(16*64)
    }
    float2 ex;                                          // intra-wave exclusive
    ex.x = __shfl_up(a.x, 1u, 64);
    ex.y = __shfl_up(a.y, 1u, 64);
    if (lane == 0) { ex.x = 0.f; ex.y = 0.f; }
    if (lane == 63) wsagg[wav] = a;                     // wave aggregate
    __syncthreads();   // the ONLY barrier (wagg + wsagg ready)

    // ---- State entering this wave: S = fold(warmup) then fold(earlier waves).
    float2 S = make_float2(0.f, 0.f);
    #pragma unroll
    for (int j = 0; j < WCH_; ++j) S = mat_apply_add(AL, S, wagg[j]);
    #pragma unroll
    for (int u = 0; u < NW_ - 1; ++u)
        if (wav > u) S = mat_apply_add(Pw, S, wsagg[u]);  // Pw = A^1024 = AL^64

    // ---- Entering state E = ex + AL^lane * S.
    float2 E = mat_apply_add(R, S, ex);

    // ---- Correct outputs in-register, store directly (nontemporal float4).
    {
        float c1 = E.x, c2 = E.y;
        #pragma unroll
        for (int i = 0; i < L_; ++i) {
            float nc1 = cf.p * c1;
            float nc2 = fmaf(cf.q, c1, cf.r * c2);
            c1 = nc1; c2 = nc2;
            y2l[i] = (y2l[i] + c2) * gain;
        }
    }
    f32x4* og = (f32x4*)(out + tile_start + (long)t * L_);
    f32x4 o0; o0.x = y2l[0];  o0.y = y2l[1];  o0.z = y2l[2];  o0.w = y2l[3];
    f32x4 o1; o1.x = y2l[4];  o1.y = y2l[5];  o1.z = y2l[6];  o1.w = y2l[7];
    f32x4 o2; o2.x = y2l[8];  o2.y = y2l[9];  o2.z = y2l[10]; o2.w = y2l[11];
    f32x4 o3; o3.x = y2l[12]; o3.y = y2l[13]; o3.z = y2l[14]; o3.w = y2l[15];
    __builtin_nontemporal_store(o0, og + 0);
    __builtin_nontemporal_store(o1, og + 1);
    __builtin_nontemporal_store(o2, og + 2);
    __builtin_nontemporal_store(o3, og + 3);
}

extern "C" void kernel_launch(void* const* d_in, const int* in_sizes, int n_in,
                              void* d_out, int out_size, void* d_ws, size_t ws_size,
                              hipStream_t stream) {
    const float* x   = (const float*)d_in[0];
    const float* cfp = (const float*)d_in[1];
    const float* bwp = (const float*)d_in[2];
    const float* gp  = (const float*)d_in[3];
    const int*   srp = (const int*)d_in[4];
    float* out = (float*)d_out;

    dim3 blk(NT_), grd(B_ * TPR_);        // 8192 blocks
    bp_kernel<<<grd, blk, 0, stream>>>(x, out, cfp, bwp, gp, srp);
}

// Round 4
// 239.053 us; speedup vs baseline: 1.1935x; 1.1935x over previous
//
#include <hip/hip_runtime.h>
#include <math.h>

// Problem constants (match setup_inputs: B=128, T=262144).
#define B_    128
#define T_    262144
#define L_    16                 // samples per thread
#define NT_   256                // threads per block
#define WCH_  16                 // warmup chunks per tile (256 samples; A^256 ~ 1e-11)
#define OT_   (NT_ * L_)         // output tile = 4096 samples
#define TPR_  (T_ / OT_)         // 64 tiles per row
#define NW_   (NT_ / 64)         // 4 waves per block
#define STR_  (L_ + 1)           // padded LDS chunk stride = 17 floats (conflict-free, r1)

typedef float f32x4 __attribute__((ext_vector_type(4)));

struct Coef {
    float bh0, bh1;              // highpass input coefs
    float p, q, r;               // transition matrix [[p,0],[q,r]]
    float blc0, blc1;            // y2 direct input coefs: bl0*bh0, bl0*bh1
};

// One IIR step; y1,y2 depend only on previous-iteration state (expanded form).
__device__ inline void iir_step(const Coef& c, float xt, float& x_prev,
                                float& y1, float& y2) {
    float c1 = fmaf(c.bh0,  xt, c.bh1  * x_prev);
    float cx = fmaf(c.blc0, xt, c.blc1 * x_prev);
    float ny1 = fmaf(c.p, y1, c1);
    float ny2 = fmaf(c.q, y1, fmaf(c.r, y2, cx));
    y1 = ny1; y2 = ny2; x_prev = xt;
}

// Lower-triangular 2x2 as (p,q,r) = [[p,0],[q,r]]. Powers of one A commute.
struct Mat { float p, q, r; };
__device__ inline Mat mat_sq(Mat m) {
    Mat o; o.p = m.p * m.p; o.q = m.q * (m.p + m.r); o.r = m.r * m.r; return o;
}
__device__ inline Mat mat_mul(Mat a, Mat b) {   // a*b
    Mat o; o.p = a.p * b.p; o.q = fmaf(a.q, b.p, a.r * b.q); o.r = a.r * b.r;
    return o;
}
__device__ inline float2 mat_apply_add(Mat m, float2 v, float2 add) {  // m*v+add
    float2 o;
    o.x = fmaf(m.p, v.x, add.x);
    o.y = fmaf(m.q, v.x, fmaf(m.r, v.y, add.y));
    return o;
}

__global__ __launch_bounds__(NT_, 8) void bp_kernel(
        const float* __restrict__ x, float* __restrict__ out,
        const float* __restrict__ cfp, const float* __restrict__ bwp,
        const float* __restrict__ gp, const int* __restrict__ srp) {
    __shared__ float  ys[NT_ * STR_];      // 17,408 B output transpose tile
    __shared__ float2 wagg[WCH_];          // warmup chunk aggregates
    __shared__ float2 wsagg[NW_];          // per-wave scan aggregates

    const int blk  = blockIdx.x;
    const int row  = blk >> 6;             // / TPR_
    const int ti   = blk & (TPR_ - 1);
    const int t    = threadIdx.x;
    const int lane = t & 63;
    const int wav  = t >> 6;
    const long tile_start = (long)row * T_ + (long)ti * OT_;
    const float* xb = x + tile_start;

    // ---- Issue ALL global loads up-front (latency hidden under coef math).
    // Own segment: 16 contiguous floats = 4 float4 (64B-aligned).
    const f32x4* xg = (const f32x4*)(xb + t * L_);
    f32x4 v0 = xg[0], v1 = xg[1], v2 = xg[2], v3 = xg[3];
    // Warmup segment for threads 0..15 (zeros for first tile of a row: exact).
    f32x4 w0 = (f32x4)(0.f), w1 = w0, w2 = w0, w3 = w0;
    if (t < WCH_ && ti != 0) {
        const f32x4* wg = (const f32x4*)(xb - WCH_ * L_ + t * L_);
        w0 = wg[0]; w1 = wg[1]; w2 = wg[2]; w3 = wg[3];
    }
    // Boundary sample (last elem of previous chunk): neighbor lane's v3.w.
    // Lane-0 threads fall back to a scalar global load.
    float xp = __shfl_up(v3.w, 1u, 64);
    if (lane == 0) xp = (ti != 0 || t != 0) ? xb[t * L_ - 1] : 0.f;

    // ---- Filter coefficients, per-thread (uniform; overlaps load latency).
    Coef cf;
    {
        const float PIH = 1.57079632679489661923f;  // pi/2
        float cfv = *cfp, bwv = *bwp;
        float nyq = 0.5f * (float)(*srp);
        float K1 = tanf(PIH * (cfv - 0.5f * bwv) / nyq);
        float K2 = tanf(PIH * (cfv + 0.5f * bwv) / nyq);
        float inv1 = 1.0f / (K1 + 1.0f);
        float ah1 = (K1 - 1.0f) * inv1;
        float inv2 = 1.0f / (K2 + 1.0f);
        float bl0 = K2 * inv2;               // == bl1
        float al1 = (K2 - 1.0f) * inv2;
        cf.bh0 = inv1;
        cf.bh1 = -inv1;
        cf.p = -ah1;
        cf.q = bl0 - bl0 * ah1;              // bl0*(1 - ah1)
        cf.r = -al1;
        cf.blc0 = bl0 * inv1;
        cf.blc1 = -bl0 * inv1;
    }
    const float gain = *gp;

    // ---- Matrix powers (also overlaps load latency).
    Mat A  = { cf.p, cf.q, cf.r };
    Mat AL = A;
    #pragma unroll
    for (int k = 0; k < 4; ++k) AL = mat_sq(AL);        // A^16 = A^L
    // R = AL^lane by binary powers (6 bits).
    Mat R = { 1.f, 0.f, 1.f };
    {
        Mat Mp = AL;
        unsigned b = (unsigned)lane;
        #pragma unroll
        for (int k = 0; k < 6; ++k) {
            if (b & 1u) R = mat_mul(Mp, R);
            b >>= 1u;
            if (k < 5) Mp = mat_sq(Mp);
        }
    }

    // ---- Local scan of own chunk from zero state; y2 locals stay in VGPRs.
    float xa[L_];
    xa[0]=v0.x; xa[1]=v0.y; xa[2]=v0.z; xa[3]=v0.w;
    xa[4]=v1.x; xa[5]=v1.y; xa[6]=v1.z; xa[7]=v1.w;
    xa[8]=v2.x; xa[9]=v2.y; xa[10]=v2.z; xa[11]=v2.w;
    xa[12]=v3.x; xa[13]=v3.y; xa[14]=v3.z; xa[15]=v3.w;
    float y2l[L_];
    float y1 = 0.f, y2 = 0.f;
    {
        float xprev = xp;
        #pragma unroll
        for (int i = 0; i < L_; ++i) {
            iir_step(cf, xa[i], xprev, y1, y2);
            y2l[i] = y2;
        }
    }

    // ---- Warmup chunk scans: threads 0..15 (registers, shuffle boundary).
    float wxp = __shfl_up(w3.w, 1u, 64);    // lane t gets lane t-1's last sample
    if (t < WCH_) {
        float wa[L_];
        wa[0]=w0.x; wa[1]=w0.y; wa[2]=w0.z; wa[3]=w0.w;
        wa[4]=w1.x; wa[5]=w1.y; wa[6]=w1.z; wa[7]=w1.w;
        wa[8]=w2.x; wa[9]=w2.y; wa[10]=w2.z; wa[11]=w2.w;
        wa[12]=w3.x; wa[13]=w3.y; wa[14]=w3.z; wa[15]=w3.w;
        float wy1 = 0.f, wy2 = 0.f;
        float wp = (t == 0) ? 0.f : wxp;
        #pragma unroll
        for (int i = 0; i < L_; ++i) iir_step(cf, wa[i], wp, wy1, wy2);
        wagg[t] = make_float2(wy1, wy2);
    }

    // ---- Intra-wave inclusive scan via shuffles (no barriers).
    float2 a = make_float2(y1, y2);
    Mat Pw = AL;
    #pragma unroll
    for (int o = 1; o < 64; o <<= 1) {
        float vx = __shfl_up(a.x, (unsigned)o, 64);
        float vy = __shfl_up(a.y, (unsigned)o, 64);
        if (lane >= o) {
            a.y = fmaf(Pw.q, vx, fmaf(Pw.r, vy, a.y));
            a.x = fmaf(Pw.p, vx, a.x);
        }
        Pw = mat_sq(Pw);                                // after loop: A^(16*64)
    }
    float2 ex;                                          // intra-wave exclusive
    ex.x = __shfl_up(a.x, 1u, 64);
    ex.y = __shfl_up(a.y, 1u, 64);
    if (lane == 0) { ex.x = 0.f; ex.y = 0.f; }
    if (lane == 63) wsagg[wav] = a;                     // wave aggregate
    __syncthreads();   // barrier 1 (wagg + wsagg ready)

    // ---- State entering this wave: S = fold(warmup) then fold(earlier waves).
    float2 S = make_float2(0.f, 0.f);
    #pragma unroll
    for (int j = 0; j < WCH_; ++j) S = mat_apply_add(AL, S, wagg[j]);
    #pragma unroll
    for (int u = 0; u < NW_ - 1; ++u)
        if (wav > u) S = mat_apply_add(Pw, S, wsagg[u]);  // Pw = A^1024 = AL^64

    // ---- Entering state E = ex + AL^lane * S.
    float2 E = mat_apply_add(R, S, ex);

    // ---- Correct outputs in-register, write into padded LDS transpose tile.
    {
        float c1 = E.x, c2 = E.y;
        float* cp = ys + t * STR_;
        #pragma unroll
        for (int i = 0; i < L_; ++i) {
            float nc1 = cf.p * c1;
            float nc2 = fmaf(cf.q, c1, cf.r * c2);
            c1 = nc1; c2 = nc2;
            cp[i] = (y2l[i] + c2) * gain;
        }
    }
    __syncthreads();   // barrier 2 (y staged)

    // ---- Coalesced nontemporal float4 stores (full-line, 1KB/instr/wave).
    f32x4* og = (f32x4*)(out + tile_start);
    #pragma unroll
    for (int k = 0; k < 4; ++k) {
        int F = t + NT_ * k;               // float4 index in tile
        int chunk = F >> 2, pos = 4 * (F & 3);
        const float* p = ys + chunk * STR_ + pos;
        f32x4 o; o.x = p[0]; o.y = p[1]; o.z = p[2]; o.w = p[3];
        __builtin_nontemporal_store(o, og + F);
    }
}

extern "C" void kernel_launch(void* const* d_in, const int* in_sizes, int n_in,
                              void* d_out, int out_size, void* d_ws, size_t ws_size,
                              hipStream_t stream) {
    const float* x   = (const float*)d_in[0];
    const float* cfp = (const float*)d_in[1];
    const float* bwp = (const float*)d_in[2];
    const float* gp  = (const float*)d_in[3];
    const int*   srp = (const int*)d_in[4];
    float* out = (float*)d_out;

    dim3 blk(NT_), grd(B_ * TPR_);        // 8192 blocks
    bp_kernel<<<grd, blk, 0, stream>>>(x, out, cfp, bwp, gp, srp);
}